// Round 14
// baseline (1122.518 us; speedup 1.0000x reference)
//
#include <hip/hip_runtime.h>
#include <hip/hip_bf16.h>
#include <stdint.h>

#define B_ 2
#define T_ 4096
#define D_ 1024
#define H_ 8
#define DH_ 128
#define L_ 2
#define BS_ 64
#define NH_ 8
#define NB_ 64
#define NC_ (NH_*NB_)
#define FF_ 4096
#define BH_ (B_*H_)

typedef __hip_bfloat16 bf16;
typedef __attribute__((ext_vector_type(8))) short short8;
typedef __attribute__((ext_vector_type(4))) float f32x4;

typedef __attribute__((address_space(3))) uint32_t lds_u32_t;
typedef const __attribute__((address_space(1))) uint32_t glb_u32_t;

__device__ __forceinline__ void async_load16(const void* g, void* l) {
  __builtin_amdgcn_global_load_lds((glb_u32_t*)g, (lds_u32_t*)l, 16, 0, 0);
}

// ---------------- diagnostic ----------------
__global__ void diag_kernel(float* __restrict__ out, float a, float b) {
  if (threadIdx.x == 0) { out[0] = a; out[1] = b; }
}

// ---------------- copy x -> x1, x2 ----------------
__global__ void copy2_kernel(const float* __restrict__ x, float* __restrict__ x1,
                             float* __restrict__ x2) {
  int idx = blockIdx.x * 256 + threadIdx.x;
  if (idx < B_ * T_ * D_ / 4) {
    float4 v = ((const float4*)x)[idx];
    ((float4*)x1)[idx] = v;
    ((float4*)x2)[idx] = v;
  }
}

// ---------------- transpose fp32 (K,N) -> bf16 (N,K) ----------------
__global__ __launch_bounds__(256)
void transpose_cvt(const float* __restrict__ src, bf16* __restrict__ dst, int K, int N) {
  __shared__ float tile[32][33];
  const int n0 = blockIdx.x * 32, k0 = blockIdx.y * 32;
  const int c = threadIdx.x & 31, r8 = threadIdx.x >> 5;
#pragma unroll
  for (int i = 0; i < 32; i += 8) tile[r8 + i][c] = src[(size_t)(k0 + r8 + i) * N + n0 + c];
  __syncthreads();
#pragma unroll
  for (int i = 0; i < 32; i += 8)
    dst[(size_t)(n0 + r8 + i) * K + k0 + c] = __float2bfloat16(tile[c][r8 + i]);
}

// ---------------- LayerNorm fp32 row -> bf16 ----------------
__global__ __launch_bounds__(256)
void ln_kernel(const float* __restrict__ x, const float* __restrict__ g,
               const float* __restrict__ b, bf16* __restrict__ h) {
  __shared__ float red[8];
  const int row = blockIdx.x;
  const float* xr = x + (size_t)row * D_;
  const int tid = threadIdx.x;
  float4 xv = *(const float4*)(xr + tid * 4);
  float vals[4] = {xv.x, xv.y, xv.z, xv.w};
  float s = vals[0] + vals[1] + vals[2] + vals[3];
  float s2 = vals[0]*vals[0] + vals[1]*vals[1] + vals[2]*vals[2] + vals[3]*vals[3];
#pragma unroll
  for (int o = 1; o < 64; o <<= 1) { s += __shfl_xor(s, o, 64); s2 += __shfl_xor(s2, o, 64); }
  const int w = tid >> 6, lane = tid & 63;
  if (lane == 0) { red[w] = s; red[4 + w] = s2; }
  __syncthreads();
  s = red[0] + red[1] + red[2] + red[3];
  s2 = red[4] + red[5] + red[6] + red[7];
  const float mean = s * (1.0f / D_);
  const float var = s2 * (1.0f / D_) - mean * mean;
  const float rstd = rsqrtf(var + 1e-5f);
  bf16* hr = h + (size_t)row * D_;
#pragma unroll
  for (int i = 0; i < 4; ++i) {
    const int c = tid * 4 + i;
    hr[c] = __float2bfloat16((vals[i] - mean) * rstd * g[c] + b[c]);
  }
}

// ======== 256x256 phase-split GEMM with COUNTED vmcnt (T3+T4+T5) ========
// BK=64, 8 waves, 2 LDS buffers (128 KiB, 1 block/CU). Per K-step: 4 phases.
// Issue order per iter t (per wave, 1 load/thread/pass):
//   p0:[B0,B1] p1:[B2,B3] | mid: vmcnt(4)+s_barrier (A1,A3 of tile t land) |
//   p2:[A0,A2] p3:[A1,A3] | boundary: vmcnt(2)+s_barrier (B+A0,A2 of t+1 land).
// Loads never drain to 0 in the loop; raw s_barrier (NOT __syncthreads) so the
// compiler cannot reinsert the vmcnt(0). Phase p reads A-rows {32p..} = passes
// {p>>1, 2+(p>>1)}; B read fully at p0 — dependency ledger verified per-wave.
// EPI 3: gelu(val+bias)->bf16 (FF1). EPI 6: fused qk+v head-transform (N=2048).
template<int EPI>
__global__ __launch_bounds__(512)
void gemm256p(const bf16* __restrict__ A, const bf16* __restrict__ Bt,
              void* __restrict__ dst, const float* __restrict__ bias,
              float* __restrict__ resid, int M, int N, int K) {
  __shared__ __align__(16) bf16 sA[2][256 * 64];
  __shared__ __align__(16) bf16 sB[2][256 * 64];
  const int tid = threadIdx.x;

  // T1 swizzle (256-tiles)
  const int GX = gridDim.x;
  const int nwg = GX * gridDim.y;
  const int orig = blockIdx.y * GX + blockIdx.x;
  int m0, n0;
  if ((nwg & 7) == 0 && (gridDim.y & 7) == 0) {
    const int cpx = nwg >> 3;
    const int lin = (orig & 7) * cpx + (orig >> 3);
    const int gsz = GX << 3;
    const int group = lin / gsz;
    const int rem = lin - group * gsz;
    m0 = ((group << 3) + (rem & 7)) << 8;
    n0 = (rem >> 3) << 8;
  } else {
    m0 = blockIdx.y << 8;
    n0 = blockIdx.x << 8;
  }

  const int lane = tid & 63;
  const int wv = tid >> 6;
  const int wm = (wv >> 2) << 7;      // 0 / 128
  const int wn = (wv & 3) << 6;       // 0 / 64 / 128 / 192
  const int l15 = lane & 15, lq = lane >> 4;

  f32x4 acc[8][4];
#pragma unroll
  for (int i = 0; i < 8; ++i)
#pragma unroll
    for (int j = 0; j < 4; ++j) acc[i][j] = (f32x4){0.f, 0.f, 0.f, 0.f};

  const bf16* Ab = A + (size_t)m0 * K;
  const bf16* Bb = Bt + (size_t)n0 * K;
  const int rs = tid >> 3, ch0 = tid & 7;

  // pass q stages rows q*64..q*64+63 of one array; LDS dst linear in tid.
  auto stageA = [&](int t, int q) {
    const int r = (q << 6) + rs;
    const size_t ga = (size_t)r * K + (size_t)((ch0 ^ (r & 7)) << 3) + ((size_t)t << 6);
    async_load16(Ab + ga, (char*)sA[t & 1] + (q << 13) + tid * 16);
  };
  auto stageB = [&](int t, int q) {
    const int r = (q << 6) + rs;
    const size_t ga = (size_t)r * K + (size_t)((ch0 ^ (r & 7)) << 3) + ((size_t)t << 6);
    async_load16(Bb + ga, (char*)sB[t & 1] + (q << 13) + tid * 16);
  };

  short8 bfr[4][2];

  // prologue: tile 0 fully staged, single full drain (outside main loop)
#pragma unroll
  for (int q = 0; q < 4; ++q) { stageB(0, q); stageA(0, q); }
  asm volatile("s_waitcnt vmcnt(0)" ::: "memory");
  __builtin_amdgcn_s_barrier();

  const int NT = K >> 6;
  for (int t = 0; t < NT; ++t) {
    const int b = t & 1;
    const bool more = (t + 1 < NT);
    const bf16* __restrict__ pA = sA[b];
    const bf16* __restrict__ pB = sB[b];

    // ---- phase 0: stage B0,B1(t+1); load all B frags; MFMA rows 0,1 ----
    if (more) { stageB(t + 1, 0); stageB(t + 1, 1); }
#pragma unroll
    for (int ni = 0; ni < 4; ++ni)
#pragma unroll
      for (int kk = 0; kk < 2; ++kk) {
        const int row = wn + ni * 16 + l15;
        bfr[ni][kk] = *(const short8*)(pB + (row << 6) + (((kk * 4 + lq) ^ (row & 7)) << 3));
      }
#pragma unroll
    for (int m2 = 0; m2 < 2; ++m2) {
      short8 af[2];
      const int row = wm + m2 * 16 + l15;
#pragma unroll
      for (int kk = 0; kk < 2; ++kk)
        af[kk] = *(const short8*)(pA + (row << 6) + (((kk * 4 + lq) ^ (row & 7)) << 3));
      __builtin_amdgcn_s_setprio(1);
#pragma unroll
      for (int ni = 0; ni < 4; ++ni)
#pragma unroll
        for (int kk = 0; kk < 2; ++kk)
          acc[m2][ni] = __builtin_amdgcn_mfma_f32_16x16x32_bf16(af[kk], bfr[ni][kk], acc[m2][ni], 0, 0, 0);
      __builtin_amdgcn_s_setprio(0);
    }

    // ---- phase 1: stage B2,B3(t+1); MFMA rows 2,3 ----
    if (more) { stageB(t + 1, 2); stageB(t + 1, 3); }
#pragma unroll
    for (int m2 = 0; m2 < 2; ++m2) {
      short8 af[2];
      const int row = wm + (2 + m2) * 16 + l15;
#pragma unroll
      for (int kk = 0; kk < 2; ++kk)
        af[kk] = *(const short8*)(pA + (row << 6) + (((kk * 4 + lq) ^ (row & 7)) << 3));
      __builtin_amdgcn_s_setprio(1);
#pragma unroll
      for (int ni = 0; ni < 4; ++ni)
#pragma unroll
        for (int kk = 0; kk < 2; ++kk)
          acc[2 + m2][ni] = __builtin_amdgcn_mfma_f32_16x16x32_bf16(af[kk], bfr[ni][kk], acc[2 + m2][ni], 0, 0, 0);
      __builtin_amdgcn_s_setprio(0);
    }

    // ---- mid sync: A-passes 1,3 of tile t must land (issued iter t-1 p3) ----
    if (more) asm volatile("s_waitcnt vmcnt(4)" ::: "memory");
    else      asm volatile("s_waitcnt vmcnt(0)" ::: "memory");
    __builtin_amdgcn_s_barrier();

    // ---- phase 2: stage A0,A2(t+1); MFMA rows 4,5 ----
    if (more) { stageA(t + 1, 0); stageA(t + 1, 2); }
#pragma unroll
    for (int m2 = 0; m2 < 2; ++m2) {
      short8 af[2];
      const int row = wm + (4 + m2) * 16 + l15;
#pragma unroll
      for (int kk = 0; kk < 2; ++kk)
        af[kk] = *(const short8*)(pA + (row << 6) + (((kk * 4 + lq) ^ (row & 7)) << 3));
      __builtin_amdgcn_s_setprio(1);
#pragma unroll
      for (int ni = 0; ni < 4; ++ni)
#pragma unroll
        for (int kk = 0; kk < 2; ++kk)
          acc[4 + m2][ni] = __builtin_amdgcn_mfma_f32_16x16x32_bf16(af[kk], bfr[ni][kk], acc[4 + m2][ni], 0, 0, 0);
      __builtin_amdgcn_s_setprio(0);
    }

    // ---- phase 3: stage A1,A3(t+1); MFMA rows 6,7 ----
    if (more) { stageA(t + 1, 1); stageA(t + 1, 3); }
#pragma unroll
    for (int m2 = 0; m2 < 2; ++m2) {
      short8 af[2];
      const int row = wm + (6 + m2) * 16 + l15;
#pragma unroll
      for (int kk = 0; kk < 2; ++kk)
        af[kk] = *(const short8*)(pA + (row << 6) + (((kk * 4 + lq) ^ (row & 7)) << 3));
      __builtin_amdgcn_s_setprio(1);
#pragma unroll
      for (int ni = 0; ni < 4; ++ni)
#pragma unroll
        for (int kk = 0; kk < 2; ++kk)
          acc[6 + m2][ni] = __builtin_amdgcn_mfma_f32_16x16x32_bf16(af[kk], bfr[ni][kk], acc[6 + m2][ni], 0, 0, 0);
      __builtin_amdgcn_s_setprio(0);
    }

    // ---- boundary: B(t+1)+A0,A2(t+1) must land; A1,A3(t+1) stay in flight ----
    if (more) {
      asm volatile("s_waitcnt vmcnt(2)" ::: "memory");
      __builtin_amdgcn_s_barrier();
    }
  }

  const int cr = lq << 2;
#pragma unroll
  for (int mi = 0; mi < 8; ++mi) {
#pragma unroll
    for (int ni = 0; ni < 4; ++ni) {
#pragma unroll
      for (int j = 0; j < 4; ++j) {
        const int r = m0 + wm + mi * 16 + cr + j;
        const int c = n0 + wn + ni * 16 + l15;
        const float val = acc[mi][ni][j];
        if (EPI == 3) {
          const float xg = val + bias[c];
          ((bf16*)dst)[(size_t)r * N + c] =
              __float2bfloat16(0.5f * xg * (1.0f + erff(xg * 0.70710678118654752440f)));
        } else if (EPI == 6) {
          const int bb = r >> 12, t2 = r & (T_ - 1);
          if (c < 1024) {
            const int hh = c >> 7, dh = c & (DH_ - 1);
            ((bf16*)dst)[(((size_t)(bb * H_ + hh)) * T_ + t2) * DH_ + dh] = __float2bfloat16(val);
          } else {
            const int c2 = c - 1024;
            const int hh = c2 >> 7, dh = c2 & (DH_ - 1);
            ((bf16*)resid)[(((size_t)(bb * H_ + hh)) * T_ + t2) * DH_ + dh] = __float2bfloat16(val);
          }
        }
      }
    }
  }
}

// ---------------- GEMM (2-phase 128x128, proven): C = A @ Bt^T ----------------
// EPI 0: head-transform bf16 out; 2: resid += val + bias; 3: gelu -> bf16;
// EPI 4: plain bf16 out; EPI 5: fused LSH bucket argmax; EPI 6: fused qk+v.
template<int EPI>
__global__ __launch_bounds__(512)
void gemm_bt_k(const bf16* __restrict__ A, const bf16* __restrict__ Bt,
               void* __restrict__ dst, const float* __restrict__ bias,
               float* __restrict__ resid, int M, int N, int K) {
  __shared__ __align__(16) bf16 sA[2][128 * 64];
  __shared__ __align__(16) bf16 sB[2][128 * 64];
  const int tid = threadIdx.x;

  const int GX = gridDim.x;
  const int nwg = GX * gridDim.y;
  const int orig = blockIdx.y * GX + blockIdx.x;
  int m0, n0;
  if ((nwg & 7) == 0 && (gridDim.y & 7) == 0) {
    const int cpx = nwg >> 3;
    const int lin = (orig & 7) * cpx + (orig >> 3);
    const int gsz = GX << 3;
    const int group = lin / gsz;
    const int rem = lin - group * gsz;
    m0 = ((group << 3) + (rem & 7)) << 7;
    n0 = (rem >> 3) << 7;
  } else {
    m0 = blockIdx.y << 7;
    n0 = blockIdx.x << 7;
  }

  const int lane = tid & 63;
  const int wv = tid >> 6;
  const int wm = (wv >> 2) << 6;
  const int wn = (wv & 3) << 5;
  const int l15 = lane & 15, lq = lane >> 4;

  f32x4 acc[4][2];
#pragma unroll
  for (int i = 0; i < 4; ++i)
#pragma unroll
    for (int j = 0; j < 2; ++j) acc[i][j] = (f32x4){0.f, 0.f, 0.f, 0.f};

  const bf16* Ab = A + (size_t)m0 * K;
  const bf16* Bb = Bt + (size_t)n0 * K;

  const int r0s = tid >> 3, ch0 = tid & 7;
  const int r1s = r0s + 64;
  const size_t sa0 = (size_t)r0s * K + (size_t)((ch0 ^ (r0s & 7)) << 3);
  const size_t sa1 = (size_t)r1s * K + (size_t)((ch0 ^ (r1s & 7)) << 3);

  auto stage = [&](int t) {
    const int b = t & 1;
    const size_t ko = (size_t)t << 6;
    async_load16(Ab + sa0 + ko, (char*)sA[b] + tid * 16);
    async_load16(Ab + sa1 + ko, (char*)sA[b] + (tid + 512) * 16);
    async_load16(Bb + sa0 + ko, (char*)sB[b] + tid * 16);
    async_load16(Bb + sa1 + ko, (char*)sB[b] + (tid + 512) * 16);
  };

  auto compute = [&](int b) {
    const bf16* __restrict__ pA = sA[b];
    const bf16* __restrict__ pB = sB[b];
#pragma unroll
    for (int kk = 0; kk < 2; ++kk) {
      short8 af[4], bfr[2];
#pragma unroll
      for (int mi = 0; mi < 4; ++mi) {
        const int row = wm + mi * 16 + l15;
        const int chunk = (kk * 4 + lq) ^ (row & 7);
        af[mi] = *(const short8*)(pA + (row << 6) + (chunk << 3));
      }
#pragma unroll
      for (int ni = 0; ni < 2; ++ni) {
        const int row = wn + ni * 16 + l15;
        const int chunk = (kk * 4 + lq) ^ (row & 7);
        bfr[ni] = *(const short8*)(pB + (row << 6) + (chunk << 3));
      }
#pragma unroll
      for (int mi = 0; mi < 4; ++mi)
#pragma unroll
        for (int ni = 0; ni < 2; ++ni)
          acc[mi][ni] = __builtin_amdgcn_mfma_f32_16x16x32_bf16(af[mi], bfr[ni], acc[mi][ni], 0, 0, 0);
    }
  };

  stage(0);
  __syncthreads();
  const int NT = K >> 6;
  for (int t = 0; t < NT; ++t) {
    if (t + 1 < NT) stage(t + 1);
    compute(t & 1);
    if (t + 1 < NT) __syncthreads();
  }

  const int cr = lq << 2;
  if (EPI == 5) {
    const int hh2 = (n0 + wn) >> 5;
#pragma unroll
    for (int mi = 0; mi < 4; ++mi) {
#pragma unroll
      for (int j = 0; j < 4; ++j) {
        const float v0 = acc[mi][0][j], v1 = acc[mi][1][j];
        float bmx = v0; int imx = l15;
        if (v1 > bmx) { bmx = v1; imx = 16 + l15; }
        float bmn = v0; int imn = l15;
        if (v1 < bmn) { bmn = v1; imn = 16 + l15; }
#pragma unroll
        for (int o = 1; o < 16; o <<= 1) {
          const float ov = __shfl_xor(bmx, o, 64); const int oi = __shfl_xor(imx, o, 64);
          if (ov > bmx || (ov == bmx && oi < imx)) { bmx = ov; imx = oi; }
          const float ov2 = __shfl_xor(bmn, o, 64); const int oi2 = __shfl_xor(imn, o, 64);
          if (ov2 < bmn || (ov2 == bmn && oi2 < imn)) { bmn = ov2; imn = oi2; }
        }
        if (l15 == 0) {
          const int r = m0 + wm + mi * 16 + cr + j;
          const int bh = r >> 12, t2 = r & (T_ - 1);
          const int bkt = (bmx >= -bmn) ? imx : 32 + imn;
          ((uint8_t*)dst)[((size_t)(bh * 8 + hh2) << 12) + t2] = (uint8_t)bkt;
        }
      }
    }
    return;
  }

#pragma unroll
  for (int mi = 0; mi < 4; ++mi) {
#pragma unroll
    for (int ni = 0; ni < 2; ++ni) {
#pragma unroll
      for (int j = 0; j < 4; ++j) {
        const int r = m0 + wm + mi * 16 + cr + j;
        const int c = n0 + wn + ni * 16 + l15;
        float val = acc[mi][ni][j];
        if (EPI == 0) {
          const int bb = r >> 12, t2 = r & (T_ - 1);
          const int hh = c >> 7, dh = c & (DH_ - 1);
          ((bf16*)dst)[(((size_t)(bb * H_ + hh)) * T_ + t2) * DH_ + dh] = __float2bfloat16(val);
        } else if (EPI == 2) {
          resid[(size_t)r * N + c] += val + bias[c];
        } else if (EPI == 3) {
          const float xg = val + bias[c];
          ((bf16*)dst)[(size_t)r * N + c] =
              __float2bfloat16(0.5f * xg * (1.0f + erff(xg * 0.70710678118654752440f)));
        } else if (EPI == 4) {
          ((bf16*)dst)[(size_t)r * N + c] = __float2bfloat16(val);
        } else if (EPI == 6) {
          const int bb = r >> 12, t2 = r & (T_ - 1);
          if (c < 1024) {
            const int hh = c >> 7, dh = c & (DH_ - 1);
            ((bf16*)dst)[(((size_t)(bb * H_ + hh)) * T_ + t2) * DH_ + dh] = __float2bfloat16(val);
          } else {
            const int c2 = c - 1024;
            const int hh = c2 >> 7, dh = c2 & (DH_ - 1);
            ((bf16*)resid)[(((size_t)(bb * H_ + hh)) * T_ + t2) * DH_ + dh] = __float2bfloat16(val);
          }
        }
      }
    }
  }
}

// ---------------- bucket argmax (fallback path) ----------------
__global__ void bucket_kernel(const bf16* __restrict__ rotv, uint8_t* __restrict__ buckets) {
  const int idx = blockIdx.x * 256 + threadIdx.x;
  if (idx >= BH_ * T_ * NH_) return;
  const int row = idx >> 3, hh = idx & 7;
  const bf16* p = rotv + (size_t)row * 256 + hh * 32;
  float vmax = -3e38f, vmin = 3e38f;
  int imax = 0, imin = 0;
  for (int r = 0; r < 32; ++r) {
    const float xv = __bfloat162float(p[r]);
    if (xv > vmax) { vmax = xv; imax = r; }
    if (xv < vmin) { vmin = xv; imin = r; }
  }
  const int bkt = (vmax >= -vmin) ? imax : 32 + imin;
  const int bh = row >> 12, t = row & (T_ - 1);
  buckets[((size_t)(bh * 8 + hh) << 12) + t] = (uint8_t)bkt;
}

// ---------------- stable counting sort per (bh, hash); also inverse perm ----------------
__global__ __launch_bounds__(256)
void sort_kernel(const uint8_t* __restrict__ buckets, int* __restrict__ st,
                 int* __restrict__ inv) {
  __shared__ uint8_t bk[T_];
  __shared__ int wsum[4];
  const int tid = threadIdx.x;
  const int grp = blockIdx.x;  // bh*8 + h
  const uint8_t* src = buckets + (size_t)grp * T_;
  int* dst = st + (size_t)grp * T_;
  int* ivd = inv ? inv + (size_t)grp * T_ : nullptr;
  for (int i = tid; i < T_; i += 256) bk[i] = src[i];
  __syncthreads();
  const int lane = tid & 63, w = tid >> 6;
  const int t0 = tid * 16;
  int base = 0;
  for (int b = 0; b < 64; ++b) {
    int cnt = 0;
#pragma unroll
    for (int j = 0; j < 16; ++j) cnt += (bk[t0 + j] == b) ? 1 : 0;
    int incl = cnt;
    for (int o = 1; o < 64; o <<= 1) {
      int vv = __shfl_up(incl, o, 64);
      if (lane >= o) incl += vv;
    }
    if (lane == 63) wsum[w] = incl;
    __syncthreads();
    int wo = 0;
    for (int i = 0; i < w; ++i) wo += wsum[i];
    const int tot = wsum[0] + wsum[1] + wsum[2] + wsum[3];
    int pos = base + wo + incl - cnt;
    for (int j = 0; j < 16; ++j)
      if (bk[t0 + j] == b) {
        dst[pos] = t0 + j;
        if (ivd) ivd[t0 + j] = pos;
        ++pos;
      }
    base += tot;
    __syncthreads();
  }
}

// ---------------- qk row L2-normalize: qkn = qk/|qk|, qnorm = |qk| ----------------
__global__ __launch_bounds__(256)
void qknorm_kernel(const bf16* __restrict__ qk, bf16* __restrict__ qkn,
                   float* __restrict__ qnorm) {
  const int wid = (blockIdx.x * 256 + threadIdx.x) >> 6;
  const int lane = threadIdx.x & 63;
  if (wid >= BH_ * T_) return;
  const bf16* src = qk + (size_t)wid * DH_;
  const float a = __bfloat162float(src[2 * lane]);
  const float b = __bfloat162float(src[2 * lane + 1]);
  float ss = a * a + b * b;
#pragma unroll
  for (int o = 1; o < 64; o <<= 1) ss += __shfl_xor(ss, o, 64);
  const float nrm = sqrtf(ss);
  const float sc = 1.0f / fmaxf(nrm, 1e-12f);
  bf16* d = qkn + (size_t)wid * DH_;
  d[2 * lane] = __float2bfloat16(a * sc);
  d[2 * lane + 1] = __float2bfloat16(b * sc);
  if (lane == 0) qnorm[wid] = nrm;
}

// ================== BIG PATH: per-hash sorted-output attention ==================
// XCD-clustered 1-D grid (R11). LDS overlay + T14 split V staging (R13).
__global__ __launch_bounds__(256)
void attn_sorted(const bf16* __restrict__ qkn, const float* __restrict__ qnormg,
                 const bf16* __restrict__ v, const int* __restrict__ st,
                 bf16* __restrict__ so, float* __restrict__ lseg) {
  __shared__ __align__(16) bf16 sK[128 * 136];       // rows 0..63 -> sP; rows 64..127 -> sVT-hi
  __shared__ __align__(16) uint32_t sVTlo[64 * 68];  // sVT rows (d) 0..63
  __shared__ int stkv[128];
  __shared__ float snq[64];

  const int tid = threadIdx.x;
  const int lin = blockIdx.x;
  const int xcd = lin & 7;
  const int wq = lin >> 3;
  const int bh = xcd + ((wq >> 9) << 3);
  const int rem = wq & 511;
  const int hh = rem >> 6;
  const int cb = rem & 63;

  const int cg = hh * NB_ + cb;
  const int pg = (cg + NC_ - 1) & (NC_ - 1);
  const int* stb = st + (size_t)bh * (NH_ * T_);
  if (tid < 128) {
    const int p = (tid < 64) ? (cg * BS_ + tid) : (pg * BS_ + tid - 64);
    stkv[tid] = stb[p];
  }
  __syncthreads();

  const size_t vbase = (size_t)bh * T_ * DH_;
  if (tid < 64) snq[tid] = qnormg[(size_t)bh * T_ + stkv[tid]];
  {
    const int part = tid & 15, row = tid >> 4;
    for (int r0 = 0; r0 < 128; r0 += 16) {
      const int rr = r0 + row;
      const int t = stkv[rr];
      *(float4*)&sK[rr * 136 + part * 8] = *(const float4*)(qkn + vbase + (size_t)t * DH_ + part * 8);
    }
  }
  float4 va[4], vb[4];
#pragma unroll
  for (int it = 0; it < 4; ++it) {
    const int idx = it * 256 + tid;
    const int g = idx & 15, kp = idx >> 4;
    va[it] = *(const float4*)(v + vbase + (size_t)stkv[2 * kp] * DH_ + g * 8);
    vb[it] = *(const float4*)(v + vbase + (size_t)stkv[2 * kp + 1] * DH_ + g * 8);
  }
  __syncthreads();

  const int lane = tid & 63;
  const int w = tid >> 6;
  const int l15 = lane & 15, lq = lane >> 4;

  f32x4 acc[8];
#pragma unroll
  for (int i = 0; i < 8; ++i) acc[i] = (f32x4){0.f, 0.f, 0.f, 0.f};
#pragma unroll
  for (int kk = 0; kk < 4; ++kk) {
    short8 af = *(const short8*)&sK[(w * 16 + l15) * 136 + lq * 8 + kk * 32];
#pragma unroll
    for (int ni = 0; ni < 8; ++ni) {
      short8 bf = *(const short8*)&sK[(ni * 16 + l15) * 136 + lq * 8 + kk * 32];
      acc[ni] = __builtin_amdgcn_mfma_f32_16x16x32_bf16(af, bf, acc[ni], 0, 0, 0);
    }
  }
  __syncthreads();

  bf16* sP = sK;
  uint32_t* sVThi = (uint32_t*)(sK + 64 * 136);

  float lsev[4];
  const float scale = 0.08838834764831845f;
#pragma unroll
  for (int j = 0; j < 4; ++j) {
    const int row = w * 16 + lq * 4 + j;
    const int tq = stkv[row];
    const float rowsc = scale * snq[row];
    float mx = -3.0e38f;
#pragma unroll
    for (int ni = 0; ni < 8; ++ni) {
      const int tk = stkv[ni * 16 + l15];
      float val = acc[ni][j] * rowsc;
      if (tq < tk) val = -1e9f;
      else if (tq == tk) val = -5e4f;
      acc[ni][j] = val;
      mx = fmaxf(mx, val);
    }
#pragma unroll
    for (int o = 1; o < 16; o <<= 1) mx = fmaxf(mx, __shfl_xor(mx, o, 64));
    float ex[8];
    float se = 0.f;
#pragma unroll
    for (int ni = 0; ni < 8; ++ni) { ex[ni] = __expf(acc[ni][j] - mx); se += ex[ni]; }
#pragma unroll
    for (int o = 1; o < 16; o <<= 1) se += __shfl_xor(se, o, 64);
    const float inv = 1.0f / se;
#pragma unroll
    for (int ni = 0; ni < 8; ++ni)
      sP[row * 136 + ni * 16 + l15] = __float2bfloat16(ex[ni] * inv);
    lsev[j] = mx + __logf(se);
  }

#pragma unroll
  for (int it = 0; it < 4; ++it) {
    const int idx = it * 256 + tid;
    const int g = idx & 15, kp = idx >> 4;
    const unsigned short* ua = (const unsigned short*)&va[it];
    const unsigned short* ub = (const unsigned short*)&vb[it];
    const int csw = (g & 7) << 2;
    uint32_t* vdst = (g < 8) ? (sVTlo + g * 8 * 68) : (sVThi + (g - 8) * 8 * 68);
#pragma unroll
    for (int j = 0; j < 8; ++j)
      vdst[j * 68 + (kp ^ csw)] = (uint32_t)ua[j] | ((uint32_t)ub[j] << 16);
  }
  __syncthreads();

  f32x4 acc2[8];
#pragma unroll
  for (int i = 0; i < 8; ++i) acc2[i] = (f32x4){0.f, 0.f, 0.f, 0.f};
#pragma unroll
  for (int kk = 0; kk < 4; ++kk) {
    short8 pa = *(const short8*)&sP[(w * 16 + l15) * 136 + lq * 8 + kk * 32];
#pragma unroll
    for (int ni = 0; ni < 8; ++ni) {
      const int row = ni * 16 + l15;
      const int col = (lq * 4 + kk * 16) ^ (((row >> 3) & 7) << 2);
      const uint32_t* vrow = (ni < 4) ? (sVTlo + row * 68) : (sVThi + (row - 64) * 68);
      short8 bv = *(const short8*)&vrow[col];
      acc2[ni] = __builtin_amdgcn_mfma_f32_16x16x32_bf16(pa, bv, acc2[ni], 0, 0, 0);
    }
  }

  const size_t sobase = ((size_t)(hh * BH_ + bh) * T_ + (size_t)cb * BS_) * DH_;
#pragma unroll
  for (int j = 0; j < 4; ++j) {
    const int row = w * 16 + lq * 4 + j;
    if (l15 == 0)
      lseg[(size_t)(hh * BH_ + bh) * T_ + cb * BS_ + row] = lsev[j];
    bf16* orow = so + sobase + (size_t)row * DH_;
#pragma unroll
    for (int ni = 0; ni < 8; ++ni) {
      bf16 hv = __float2bfloat16(acc2[ni][j]);
      __builtin_nontemporal_store(*(unsigned short*)&hv,
                                  (unsigned short*)(orow + ni * 16 + l15));
    }
  }
}

// combine across hashes: one wave per token; gather 8 so-rows via inverse perm.
__global__ __launch_bounds__(256)
void combine2_kernel(const bf16* __restrict__ so, const float* __restrict__ lseg,
                     const int* __restrict__ ipos, bf16* __restrict__ ocomb) {
  const int gw = (blockIdx.x * 256 + threadIdx.x) >> 6;
  const int lane = threadIdx.x & 63;
  if (gw >= BH_ * T_) return;
  const int bh = gw >> 12, t = gw & (T_ - 1);
  float lse8 = -3.0e38f;
  int p8 = 0;
  if (lane < 8) {
    p8 = ipos[((size_t)bh * NH_ + lane) * T_ + t];
    lse8 = lseg[((size_t)lane * BH_ + bh) * T_ + p8];
  }
  float m = -3.0e38f;
#pragma unroll
  for (int h = 0; h < 8; ++h) m = fmaxf(m, __shfl(lse8, h, 64));
  float s = 0.f;
#pragma unroll
  for (int h = 0; h < 8; ++h) s += __expf(__shfl(lse8, h, 64) - m);
  const float invs = 1.0f / s;
  float a0 = 0.f, a1 = 0.f;
#pragma unroll
  for (int h = 0; h < 8; ++h) {
    const int ph = __shfl(p8, h, 64);
    const float wh = __expf(__shfl(lse8, h, 64) - m) * invs;
    const unsigned short* rp =
        (const unsigned short*)(so + (((size_t)h * BH_ + bh) * T_ + ph) * DH_ + lane * 2);
    unsigned short u0 = __builtin_nontemporal_load(rp);
    unsigned short u1 = __builtin_nontemporal_load(rp + 1);
    a0 += wh * __bfloat162float(*(const bf16*)&u0);
    a1 += wh * __bfloat162float(*(const bf16*)&u1);
  }
  const int bb = bh >> 3, hd = bh & 7;
  bf16* dp = ocomb + ((size_t)(bb * T_ + t)) * D_ + hd * DH_ + lane * 2;
  dp[0] = __float2bfloat16(a0);
  dp[1] = __float2bfloat16(a1);
}

// ================== FALLBACK PATH kernels (unchanged) ==================
__global__ __launch_bounds__(256)
void attn_kernel(const bf16* __restrict__ qkn, const float* __restrict__ qnormg,
                 const bf16* __restrict__ v, const int* __restrict__ st,
                 float* __restrict__ mg, float* __restrict__ sg,
                 float* __restrict__ oac, int hh) {
  __shared__ __align__(16) bf16 sK[128 * 136];
  __shared__ __align__(16) uint32_t sVT[128][68];
  __shared__ int stkv[128];
  __shared__ float snq[64];

  const int tid = threadIdx.x;
  const int cb = blockIdx.x;
  const int bh = blockIdx.y;
  const int cg = hh * NB_ + cb;
  const int pg = (cg + NC_ - 1) & (NC_ - 1);
  const int* stb = st + (size_t)bh * (NH_ * T_);
  if (tid < 128) {
    const int p = (tid < 64) ? (cg * BS_ + tid) : (pg * BS_ + tid - 64);
    stkv[tid] = stb[p];
  }
  __syncthreads();

  const size_t vbase = (size_t)bh * T_ * DH_;
  if (tid < 64) snq[tid] = qnormg[(size_t)bh * T_ + stkv[tid]];
  {
    const int part = tid & 15, row = tid >> 4;
    for (int r0 = 0; r0 < 128; r0 += 16) {
      const int rr = r0 + row;
      const int t = stkv[rr];
      *(float4*)&sK[rr * 136 + part * 8] = *(const float4*)(qkn + vbase + (size_t)t * DH_ + part * 8);
    }
  }
  {
    for (int it = 0; it < 4; ++it) {
      const int idx = it * 256 + tid;
      const int g = idx & 15, kp = idx >> 4;
      const int t0 = stkv[2 * kp], t1 = stkv[2 * kp + 1];
      float4 a = *(const float4*)(v + vbase + (size_t)t0 * DH_ + g * 8);
      float4 b = *(const float4*)(v + vbase + (size_t)t1 * DH_ + g * 8);
      const unsigned short* ua = (const unsigned short*)&a;
      const unsigned short* ub = (const unsigned short*)&b;
#pragma unroll
      for (int j = 0; j < 8; ++j)
        sVT[g * 8 + j][kp] = (uint32_t)ua[j] | ((uint32_t)ub[j] << 16);
    }
  }
  __syncthreads();

  const int lane = tid & 63;
  const int w = tid >> 6;
  const int l15 = lane & 15, lq = lane >> 4;

  f32x4 acc[8];
#pragma unroll
  for (int i = 0; i < 8; ++i) acc[i] = (f32x4){0.f, 0.f, 0.f, 0.f};
#pragma unroll
  for (int kk = 0; kk < 4; ++kk) {
    short8 af = *(const short8*)&sK[(w * 16 + l15) * 136 + lq * 8 + kk * 32];
#pragma unroll
    for (int ni = 0; ni < 8; ++ni) {
      short8 bf = *(const short8*)&sK[(ni * 16 + l15) * 136 + lq * 8 + kk * 32];
      acc[ni] = __builtin_amdgcn_mfma_f32_16x16x32_bf16(af, bf, acc[ni], 0, 0, 0);
    }
  }
  __syncthreads();

  bf16* sP = sK;

  float lsev[4];
  const float scale = 0.08838834764831845f;
#pragma unroll
  for (int j = 0; j < 4; ++j) {
    const int row = w * 16 + lq * 4 + j;
    const int tq = stkv[row];
    const float rowsc = scale * snq[row];
    float mx = -3.0e38f;
#pragma unroll
    for (int ni = 0; ni < 8; ++ni) {
      const int tk = stkv[ni * 16 + l15];
      float val = acc[ni][j] * rowsc;
      if (tq < tk) val = -1e9f;
      else if (tq == tk) val = -5e4f;
      acc[ni][j] = val;
      mx = fmaxf(mx, val);
    }
#pragma unroll
    for (int o = 1; o < 16; o <<= 1) mx = fmaxf(mx, __shfl_xor(mx, o, 64));
    float se = 0.f;
#pragma unroll
    for (int ni = 0; ni < 8; ++ni) se += __expf(acc[ni][j] - mx);
#pragma unroll
    for (int o = 1; o < 16; o <<= 1) se += __shfl_xor(se, o, 64);
    const float inv = 1.0f / se;
#pragma unroll
    for (int ni = 0; ni < 8; ++ni)
      sP[row * 136 + ni * 16 + l15] = __float2bfloat16(__expf(acc[ni][j] - mx) * inv);
    lsev[j] = mx + __logf(se);
  }
  __syncthreads();

  f32x4 acc2[8];
#pragma unroll
  for (int i = 0; i < 8; ++i) acc2[i] = (f32x4){0.f, 0.f, 0.f, 0.f};
#pragma unroll
  for (int kk = 0; kk < 4; ++kk) {
    short8 pa = *(const short8*)&sP[(w * 16 + l15) * 136 + lq * 8 + kk * 32];
#pragma unroll
    for (int ni = 0; ni < 8; ++ni) {
      short8 bv = *(const short8*)&sVT[ni * 16 + l15][lq * 4 + kk * 16];
      acc2[ni] = __builtin_amdgcn_mfma_f32_16x16x32_bf16(pa, bv, acc2[ni], 0, 0, 0);
    }
  }

#pragma unroll
  for (int j = 0; j < 4; ++j) {
    const int row = w * 16 + lq * 4 + j;
    const int t = stkv[row];
    const size_t gi = (size_t)bh * T_ + t;
    const float ls = lsev[j];
    float* orow = oac + gi * DH_;
    if (hh == 0) {
      if (l15 == 0) { sg[gi] = 1.0f; mg[gi] = ls; }
#pragma unroll
      for (int ni = 0; ni < 8; ++ni) orow[ni * 16 + l15] = acc2[ni][j];
    } else {
      const float mo = mg[gi];
      const float mn = fmaxf(mo, ls);
      const float al = __expf(mo - mn);
      const float be = __expf(ls - mn);
      if (l15 == 0) { sg[gi] = sg[gi] * al + be; mg[gi] = mn; }
#pragma unroll
      for (int ni = 0; ni < 8; ++ni) {
        const int c = ni * 16 + l15;
        orow[c] = orow[c] * al + be * acc2[ni][j];
      }
    }
  }
}

__global__ void combine_kernel(const float* __restrict__ oac, const float* __restrict__ sg,
                               bf16* __restrict__ ocomb) {
  const int idx = blockIdx.x * 256 + threadIdx.x;
  if (idx >= BH_ * T_ * DH_ / 4) return;
  const int rowtok = idx >> 5;
  const int gsub = idx & 31;
  const float inv = 1.0f / sg[rowtok];
  float4 ov = ((const float4*)oac)[idx];
  const int bh = rowtok >> 12, t = rowtok & (T_ - 1);
  const int bb = bh >> 3, hd = bh & 7;
  bf16* dp = ocomb + ((size_t)(bb * T_ + t)) * D_ + hd * DH_ + gsub * 4;
  dp[0] = __float2bfloat16(ov.x * inv);
  dp[1] = __float2bfloat16(ov.y * inv);
  dp[2] = __float2bfloat16(ov.z * inv);
  dp[3] = __float2bfloat16(ov.w * inv);
}

// ---------------- final mean pool ----------------
__global__ void pool_partial(const float* __restrict__ x1, const float* __restrict__ x2,
                             float* __restrict__ part) {
  const int b = blockIdx.y, slice = blockIdx.x;
  const int tid = threadIdx.x;
  float acc[4] = {0.f, 0.f, 0.f, 0.f};
  for (int r = 0; r < 32; ++r) {
    const size_t base = ((size_t)b * T_ + slice * 32 + r) * D_;
#pragma unroll
    for (int i = 0; i < 4; ++i) {
      const int c = tid + i * 256;
      acc[i] += x1[base + c] + x2[base + c];
    }
  }
#pragma unroll
  for (int i = 0; i < 4; ++i)
    part[((size_t)(b * 128 + slice)) * D_ + tid + i * 256] = acc[i];
}

__global__ void pool_reduce(const float* __restrict__ part, float* __restrict__ out) {
  const int idx = blockIdx.x * 256 + threadIdx.x;
  if (idx >= B_ * D_) return;
  const int b = idx >> 10, d = idx & 1023;
  float s = 0.f;
  for (int k = 0; k < 128; ++k) s += part[((size_t)(b * 128 + k)) * D_ + d];
  out[idx] = s * (0.5f / T_);
}

extern "C" void kernel_launch(void* const* d_in, const int* in_sizes, int n_in,
                              void* d_out, int out_size, void* d_ws, size_t ws_size,
                              hipStream_t stream) {
  (void)in_sizes; (void)n_in; (void)out_size;
  const float* x    = (const float*)d_in[0];
  const float* Wqk  = (const float*)d_in[1];
  const float* Wv   = (const float*)d_in[2];
  const float* Wout = (const float*)d_in[3];
  const float* bout = (const float*)d_in[4];
  const float* ln1g = (const float*)d_in[5];
  const float* ln1b = (const float*)d_in[6];
  const float* W1   = (const float*)d_in[7];
  const float* b1   = (const float*)d_in[8];
  const float* W2   = (const float*)d_in[9];
  const float* b2   = (const float*)d_in[10];
  const float* ln2g = (const float*)d_in[11];
  const float* ln2b = (const float*)d_in[12];
  const float* rot  = (const float*)d_in[13];
  float* out = (float*)d_out;

  char* ws = (char*)d_ws;
  const dim3 blk(256);
  const dim3 blk512(512);

  // ---------- BIG plan (~245.3 MiB): per-hash sorted outputs ----------
  {
    size_t off = 0;
    auto alloc = [&](size_t b) { size_t o = off; off += (b + 255) & ~(size_t)255; return o; };
    const size_t o_x1  = alloc((size_t)B_ * T_ * D_ * 4);
    const size_t o_x2  = alloc((size_t)B_ * T_ * D_ * 4);
    const size_t o_hq  = alloc((size_t)B_ * T_ * D_ * 2);       // h / qkn
    const size_t o_qk  = alloc((size_t)BH_ * T_ * DH_ * 2);     // qk / ocomb
    const size_t o_vv  = alloc((size_t)BH_ * T_ * DH_ * 2);     // v
    const size_t o_so  = alloc((size_t)NH_ * BH_ * T_ * DH_ * 2);  // 128 MiB, heavy aliasing
    const size_t o_lse = alloc((size_t)NH_ * BH_ * T_ * 4);
    const size_t o_st  = alloc((size_t)BH_ * NH_ * T_ * 4);
    const size_t o_ip  = alloc((size_t)BH_ * NH_ * T_ * 4);
    const size_t o_bkt = alloc((size_t)BH_ * NH_ * T_);
    const size_t o_qn  = alloc((size_t)BH_ * T_ * 4);
    const size_t o_part = alloc((size_t)B_ * 128 * D_ * 4);

    if (off <= ws_size) {
      float* x1   = (float*)(ws + o_x1);
      float* x2   = (float*)(ws + o_x2);
      bf16*  h    = (bf16*)(ws + o_hq);
      bf16*  qkn  = (bf16*)(ws + o_hq);
      bf16*  qk   = (bf16*)(ws + o_qk);
      bf16*  ocomb = (bf16*)(ws + o_qk);
      bf16*  vv   = (bf16*)(ws + o_vv);
      bf16*  so   = (bf16*)(ws + o_so);
      float* lse  = (float*)(ws + o_lse);
      int*   st   = (int*)(ws + o_st);
      int*   ip   = (int*)(ws + o_ip);
      uint8_t* bkt = (uint8_t*)(ws + o_bkt);
      float* qn   = (float*)(ws + o_qn);
      float* part = (float*)(ws + o_part);
      bf16* wqkT = (bf16*)(ws + o_so);                      // pre-attn; wvT contiguous after
      bf16* wvT  = wqkT + (size_t)D_ * D_;
      bf16* rotT = wvT + (size_t)D_ * D_;
      bf16* woT  = (bf16*)(ws + o_so);                      // post-combine2
      bf16* ffh  = (bf16*)(ws + o_so);                      // FF (64 MiB)
      bf16* w1T  = (bf16*)(ws + o_so + ((size_t)64 << 20));
      bf16* w2T  = w1T + (size_t)D_ * FF_;

      copy2_kernel<<<dim3(B_ * T_ * D_ / 4 / 256), blk, 0, stream>>>(x, x1, x2);

      for (int l = 0; l < L_; ++l) {
        transpose_cvt<<<dim3(32, 32), blk, 0, stream>>>(Wqk + (size_t)l * D_ * D_, wqkT, D_, D_);
        transpose_cvt<<<dim3(32, 32), blk, 0, stream>>>(Wv + (size_t)l * D_ * D_, wvT, D_, D_);
        transpose_cvt<<<dim3(8, 4), blk, 0, stream>>>(rot + (size_t)l * DH_ * 256, rotT, DH_, 256);

        ln_kernel<<<dim3(B_ * T_), blk, 0, stream>>>(x2, ln1g + l * D_, ln1b + l * D_, h);
        // fused QK+V projection, 256^2 counted-vmcnt pipeline (grid 8x32 = 256)
        gemm256p<6><<<dim3(8, 32), blk512, 0, stream>>>(h, wqkT, qk, nullptr, (float*)vv,
                                                        B_ * T_, 2048, D_);
        qknorm_kernel<<<dim3(BH_ * T_ / 4), blk, 0, stream>>>(qk, qkn, qn);
        gemm_bt_k<5><<<dim3(2, 512), blk512, 0, stream>>>(qkn, rotT, bkt, nullptr, nullptr, BH_ * T_, 256, DH_);
        sort_kernel<<<dim3(BH_ * NH_), blk, 0, stream>>>(bkt, st, ip);
        attn_sorted<<<dim3(NB_ * BH_ * NH_), blk, 0, stream>>>(qkn, qn, vv, st, so, lse);
        combine2_kernel<<<dim3(BH_ * T_ / 4), blk, 0, stream>>>(so, lse, ip, ocomb);
        transpose_cvt<<<dim3(32, 32), blk, 0, stream>>>(Wout + (size_t)l * D_ * D_, woT, D_, D_);
        gemm_bt_k<2><<<dim3(8, 64), blk512, 0, stream>>>(ocomb, woT, nullptr, bout + l * D_, x1, B_ * T_, D_, D_);

        transpose_cvt<<<dim3(128, 32), blk, 0, stream>>>(W1 + (size_t)l * D_ * FF_, w1T, D_, FF_);
        transpose_cvt<<<dim3(32, 128), blk, 0, stream>>>(W2 + (size_t)l * FF_ * D_, w2T, FF_, D_);
        ln_kernel<<<dim3(B_ * T_), blk, 0, stream>>>(x1, ln2g + l * D_, ln2b + l * D_, h);
        // FF1 on 256^2 counted-vmcnt pipeline (grid 16x32 = 512)
        gemm256p<3><<<dim3(16, 32), blk512, 0, stream>>>(h, w1T, ffh, b1 + l * FF_,
                                                         nullptr, B_ * T_, FF_, D_);
        gemm_bt_k<2><<<dim3(8, 64), blk512, 0, stream>>>(ffh, w2T, nullptr, b2 + l * D_, x2, B_ * T_, D_, FF_);
      }

      pool_partial<<<dim3(128, B_), blk, 0, stream>>>(x1, x2, part);
      pool_reduce<<<dim3((B_ * D_ + 255) / 256), blk, 0, stream>>>(part, out);
      return;
    }
  }

  // ---------- FALLBACK plan (~164.3 MiB) ----------
  size_t off = 0;
  auto alloc = [&](size_t b) { size_t o = off; off += (b + 255) & ~(size_t)255; return o; };
  const size_t o_x1   = alloc((size_t)B_ * T_ * D_ * 4);
  const size_t o_x2   = alloc((size_t)B_ * T_ * D_ * 4);
  const size_t o_hq   = alloc((size_t)B_ * T_ * D_ * 2);
  const size_t o_qk   = alloc((size_t)BH_ * T_ * DH_ * 2);
  const size_t o_vv   = alloc((size_t)BH_ * T_ * DH_ * 2);
  const size_t o_oac  = alloc((size_t)BH_ * T_ * DH_ * 4);
  const size_t o_st   = alloc((size_t)BH_ * NH_ * T_ * 4);
  const size_t o_bkt  = alloc((size_t)BH_ * NH_ * T_);
  const size_t o_mg   = alloc((size_t)BH_ * T_ * 4);
  const size_t o_sg   = alloc((size_t)BH_ * T_ * 4);
  const size_t o_qn   = alloc((size_t)BH_ * T_ * 4);
  const size_t o_part = alloc((size_t)B_ * 128 * D_ * 4);
  const size_t o_w    = alloc((size_t)D_ * FF_ * 2 * 2);
  if (off > ws_size) {
    diag_kernel<<<dim3(1), dim3(64), 0, stream>>>(out, (float)ws_size, (float)off);
    return;
  }

  float* x1   = (float*)(ws + o_x1);
  float* x2   = (float*)(ws + o_x2);
  bf16*  h    = (bf16*)(ws + o_hq);
  bf16*  qkn  = (bf16*)(ws + o_hq);
  bf16*  qk   = (bf16*)(ws + o_qk);
  bf16*  ocomb = (bf16*)(ws + o_qk);
  bf16*  vv   = (bf16*)(ws + o_vv);
  float* oac  = (float*)(ws + o_oac);
  bf16*  rotd = (bf16*)(ws + o_oac);
  bf16*  ffh  = (bf16*)(ws + o_qk);
  int*   st   = (int*)(ws + o_st);
  uint8_t* bkt = (uint8_t*)(ws + o_bkt);
  float* mg   = (float*)(ws + o_mg);
  float* sg   = (float*)(ws + o_sg);
  float* qn   = (float*)(ws + o_qn);
  float* part = (float*)(ws + o_part);
  bf16* wqkT = (bf16*)(ws + o_w);
  bf16* wvT  = (bf16*)(ws + o_w + (size_t)D_ * D_ * 2);
  bf16* woT  = (bf16*)(ws + o_w + (size_t)D_ * D_ * 2 * 2);
  bf16* rotT = (bf16*)(ws + o_w + (size_t)D_ * D_ * 2 * 3);
  bf16* w1T  = (bf16*)(ws + o_w);
  bf16* w2T  = (bf16*)(ws + o_w + (size_t)D_ * FF_ * 2);

  copy2_kernel<<<dim3(B_ * T_ * D_ / 4 / 256), blk, 0, stream>>>(x, x1, x2);

  for (int l = 0; l < L_; ++l) {
    transpose_cvt<<<dim3(32, 32), blk, 0, stream>>>(Wqk + (size_t)l * D_ * D_, wqkT, D_, D_);
    transpose_cvt<<<dim3(32, 32), blk, 0, stream>>>(Wv + (size_t)l * D_ * D_, wvT, D_, D_);
    transpose_cvt<<<dim3(32, 32), blk, 0, stream>>>(Wout + (size_t)l * D_ * D_, woT, D_, D_);
    transpose_cvt<<<dim3(8, 4), blk, 0, stream>>>(rot + (size_t)l * DH_ * 256, rotT, DH_, 256);

    ln_kernel<<<dim3(B_ * T_), blk, 0, stream>>>(x2, ln1g + l * D_, ln1b + l * D_, h);
    gemm_bt_k<0><<<dim3(8, 64), blk512, 0, stream>>>(h, wqkT, qk, nullptr, nullptr, B_ * T_, D_, D_);
    gemm_bt_k<0><<<dim3(8, 64), blk512, 0, stream>>>(h, wvT, vv, nullptr, nullptr, B_ * T_, D_, D_);
    qknorm_kernel<<<dim3(BH_ * T_ / 4), blk, 0, stream>>>(qk, qkn, qn);
    gemm_bt_k<4><<<dim3(2, 512), blk512, 0, stream>>>(qkn, rotT, rotd, nullptr, nullptr, BH_ * T_, 256, DH_);
    bucket_kernel<<<dim3(BH_ * T_ * NH_ / 256), blk, 0, stream>>>(rotd, bkt);
    sort_kernel<<<dim3(BH_ * NH_), blk, 0, stream>>>(bkt, st, nullptr);
    for (int hh = 0; hh < NH_; ++hh)
      attn_kernel<<<dim3(NB_, BH_), blk, 0, stream>>>(qkn, qn, vv, st, mg, sg, oac, hh);
    combine_kernel<<<dim3(BH_ * T_ * DH_ / 4 / 256), blk, 0, stream>>>(oac, sg, ocomb);
    gemm_bt_k<2><<<dim3(8, 64), blk512, 0, stream>>>(ocomb, woT, nullptr, bout + l * D_, x1, B_ * T_, D_, D_);

    transpose_cvt<<<dim3(128, 32), blk, 0, stream>>>(W1 + (size_t)l * D_ * FF_, w1T, D_, FF_);
    transpose_cvt<<<dim3(32, 128), blk, 0, stream>>>(W2 + (size_t)l * FF_ * D_, w2T, FF_, D_);

    ln_kernel<<<dim3(B_ * T_), blk, 0, stream>>>(x1, ln2g + l * D_, ln2b + l * D_, h);
    gemm_bt_k<3><<<dim3(32, 64), blk512, 0, stream>>>(h, w1T, ffh, b1 + l * FF_, nullptr, B_ * T_, FF_, D_);
    gemm_bt_k<2><<<dim3(8, 64), blk512, 0, stream>>>(ffh, w2T, nullptr, b2 + l * D_, x2, B_ * T_, D_, FF_);
  }

  pool_partial<<<dim3(128, B_), blk, 0, stream>>>(x1, x2, part);
  pool_reduce<<<dim3((B_ * D_ + 255) / 256), blk, 0, stream>>>(part, out);
}

// Round 15
// 1102.330 us; speedup vs baseline: 1.0183x; 1.0183x over previous
//
#include <hip/hip_runtime.h>
#include <hip/hip_bf16.h>
#include <stdint.h>

#define B_ 2
#define T_ 4096
#define D_ 1024
#define H_ 8
#define DH_ 128
#define L_ 2
#define BS_ 64
#define NH_ 8
#define NB_ 64
#define NC_ (NH_*NB_)
#define FF_ 4096
#define BH_ (B_*H_)

typedef __hip_bfloat16 bf16;
typedef __attribute__((ext_vector_type(8))) short short8;
typedef __attribute__((ext_vector_type(4))) float f32x4;

typedef __attribute__((address_space(3))) uint32_t lds_u32_t;
typedef const __attribute__((address_space(1))) uint32_t glb_u32_t;

__device__ __forceinline__ void async_load16(const void* g, void* l) {
  __builtin_amdgcn_global_load_lds((glb_u32_t*)g, (lds_u32_t*)l, 16, 0, 0);
}

// ---------------- diagnostic ----------------
__global__ void diag_kernel(float* __restrict__ out, float a, float b) {
  if (threadIdx.x == 0) { out[0] = a; out[1] = b; }
}

// ---------------- copy x -> x1, x2 ----------------
__global__ void copy2_kernel(const float* __restrict__ x, float* __restrict__ x1,
                             float* __restrict__ x2) {
  int idx = blockIdx.x * 256 + threadIdx.x;
  if (idx < B_ * T_ * D_ / 4) {
    float4 v = ((const float4*)x)[idx];
    ((float4*)x1)[idx] = v;
    ((float4*)x2)[idx] = v;
  }
}

// ---------------- transpose fp32 (K,N) -> bf16 (N,K) ----------------
__global__ __launch_bounds__(256)
void transpose_cvt(const float* __restrict__ src, bf16* __restrict__ dst, int K, int N) {
  __shared__ float tile[32][33];
  const int n0 = blockIdx.x * 32, k0 = blockIdx.y * 32;
  const int c = threadIdx.x & 31, r8 = threadIdx.x >> 5;
#pragma unroll
  for (int i = 0; i < 32; i += 8) tile[r8 + i][c] = src[(size_t)(k0 + r8 + i) * N + n0 + c];
  __syncthreads();
#pragma unroll
  for (int i = 0; i < 32; i += 8)
    dst[(size_t)(n0 + r8 + i) * K + k0 + c] = __float2bfloat16(tile[c][r8 + i]);
}

// ---------------- LayerNorm fp32 row -> bf16 ----------------
__global__ __launch_bounds__(256)
void ln_kernel(const float* __restrict__ x, const float* __restrict__ g,
               const float* __restrict__ b, bf16* __restrict__ h) {
  __shared__ float red[8];
  const int row = blockIdx.x;
  const float* xr = x + (size_t)row * D_;
  const int tid = threadIdx.x;
  float4 xv = *(const float4*)(xr + tid * 4);
  float vals[4] = {xv.x, xv.y, xv.z, xv.w};
  float s = vals[0] + vals[1] + vals[2] + vals[3];
  float s2 = vals[0]*vals[0] + vals[1]*vals[1] + vals[2]*vals[2] + vals[3]*vals[3];
#pragma unroll
  for (int o = 1; o < 64; o <<= 1) { s += __shfl_xor(s, o, 64); s2 += __shfl_xor(s2, o, 64); }
  const int w = tid >> 6, lane = tid & 63;
  if (lane == 0) { red[w] = s; red[4 + w] = s2; }
  __syncthreads();
  s = red[0] + red[1] + red[2] + red[3];
  s2 = red[4] + red[5] + red[6] + red[7];
  const float mean = s * (1.0f / D_);
  const float var = s2 * (1.0f / D_) - mean * mean;
  const float rstd = rsqrtf(var + 1e-5f);
  bf16* hr = h + (size_t)row * D_;
#pragma unroll
  for (int i = 0; i < 4; ++i) {
    const int c = tid * 4 + i;
    hr[c] = __float2bfloat16((vals[i] - mean) * rstd * g[c] + b[c]);
  }
}

// ---------------- GEMM (2-phase 128x128, proven optimum): C = A @ Bt^T ----------------
// EPI 0: head-transform bf16 out; 2: resid += val + bias; 3: gelu -> bf16;
// EPI 4: plain bf16 out; EPI 5: fused LSH bucket argmax; EPI 6: fused qk+v.
template<int EPI>
__global__ __launch_bounds__(512)
void gemm_bt_k(const bf16* __restrict__ A, const bf16* __restrict__ Bt,
               void* __restrict__ dst, const float* __restrict__ bias,
               float* __restrict__ resid, int M, int N, int K) {
  __shared__ __align__(16) bf16 sA[2][128 * 64];
  __shared__ __align__(16) bf16 sB[2][128 * 64];
  const int tid = threadIdx.x;

  const int GX = gridDim.x;
  const int nwg = GX * gridDim.y;
  const int orig = blockIdx.y * GX + blockIdx.x;
  int m0, n0;
  if ((nwg & 7) == 0 && (gridDim.y & 7) == 0) {
    const int cpx = nwg >> 3;
    const int lin = (orig & 7) * cpx + (orig >> 3);
    const int gsz = GX << 3;
    const int group = lin / gsz;
    const int rem = lin - group * gsz;
    m0 = ((group << 3) + (rem & 7)) << 7;
    n0 = (rem >> 3) << 7;
  } else {
    m0 = blockIdx.y << 7;
    n0 = blockIdx.x << 7;
  }

  const int lane = tid & 63;
  const int wv = tid >> 6;
  const int wm = (wv >> 2) << 6;
  const int wn = (wv & 3) << 5;
  const int l15 = lane & 15, lq = lane >> 4;

  f32x4 acc[4][2];
#pragma unroll
  for (int i = 0; i < 4; ++i)
#pragma unroll
    for (int j = 0; j < 2; ++j) acc[i][j] = (f32x4){0.f, 0.f, 0.f, 0.f};

  const bf16* Ab = A + (size_t)m0 * K;
  const bf16* Bb = Bt + (size_t)n0 * K;

  const int r0s = tid >> 3, ch0 = tid & 7;
  const int r1s = r0s + 64;
  const size_t sa0 = (size_t)r0s * K + (size_t)((ch0 ^ (r0s & 7)) << 3);
  const size_t sa1 = (size_t)r1s * K + (size_t)((ch0 ^ (r1s & 7)) << 3);

  auto stage = [&](int t) {
    const int b = t & 1;
    const size_t ko = (size_t)t << 6;
    async_load16(Ab + sa0 + ko, (char*)sA[b] + tid * 16);
    async_load16(Ab + sa1 + ko, (char*)sA[b] + (tid + 512) * 16);
    async_load16(Bb + sa0 + ko, (char*)sB[b] + tid * 16);
    async_load16(Bb + sa1 + ko, (char*)sB[b] + (tid + 512) * 16);
  };

  auto compute = [&](int b) {
    const bf16* __restrict__ pA = sA[b];
    const bf16* __restrict__ pB = sB[b];
#pragma unroll
    for (int kk = 0; kk < 2; ++kk) {
      short8 af[4], bfr[2];
#pragma unroll
      for (int mi = 0; mi < 4; ++mi) {
        const int row = wm + mi * 16 + l15;
        const int chunk = (kk * 4 + lq) ^ (row & 7);
        af[mi] = *(const short8*)(pA + (row << 6) + (chunk << 3));
      }
#pragma unroll
      for (int ni = 0; ni < 2; ++ni) {
        const int row = wn + ni * 16 + l15;
        const int chunk = (kk * 4 + lq) ^ (row & 7);
        bfr[ni] = *(const short8*)(pB + (row << 6) + (chunk << 3));
      }
#pragma unroll
      for (int mi = 0; mi < 4; ++mi)
#pragma unroll
        for (int ni = 0; ni < 2; ++ni)
          acc[mi][ni] = __builtin_amdgcn_mfma_f32_16x16x32_bf16(af[mi], bfr[ni], acc[mi][ni], 0, 0, 0);
    }
  };

  stage(0);
  __syncthreads();
  const int NT = K >> 6;
  for (int t = 0; t < NT; ++t) {
    if (t + 1 < NT) stage(t + 1);
    compute(t & 1);
    if (t + 1 < NT) __syncthreads();
  }

  const int cr = lq << 2;
  if (EPI == 5) {
    const int hh2 = (n0 + wn) >> 5;
#pragma unroll
    for (int mi = 0; mi < 4; ++mi) {
#pragma unroll
      for (int j = 0; j < 4; ++j) {
        const float v0 = acc[mi][0][j], v1 = acc[mi][1][j];
        float bmx = v0; int imx = l15;
        if (v1 > bmx) { bmx = v1; imx = 16 + l15; }
        float bmn = v0; int imn = l15;
        if (v1 < bmn) { bmn = v1; imn = 16 + l15; }
#pragma unroll
        for (int o = 1; o < 16; o <<= 1) {
          const float ov = __shfl_xor(bmx, o, 64); const int oi = __shfl_xor(imx, o, 64);
          if (ov > bmx || (ov == bmx && oi < imx)) { bmx = ov; imx = oi; }
          const float ov2 = __shfl_xor(bmn, o, 64); const int oi2 = __shfl_xor(imn, o, 64);
          if (ov2 < bmn || (ov2 == bmn && oi2 < imn)) { bmn = ov2; imn = oi2; }
        }
        if (l15 == 0) {
          const int r = m0 + wm + mi * 16 + cr + j;
          const int bh = r >> 12, t2 = r & (T_ - 1);
          const int bkt = (bmx >= -bmn) ? imx : 32 + imn;
          ((uint8_t*)dst)[((size_t)(bh * 8 + hh2) << 12) + t2] = (uint8_t)bkt;
        }
      }
    }
    return;
  }

#pragma unroll
  for (int mi = 0; mi < 4; ++mi) {
#pragma unroll
    for (int ni = 0; ni < 2; ++ni) {
#pragma unroll
      for (int j = 0; j < 4; ++j) {
        const int r = m0 + wm + mi * 16 + cr + j;
        const int c = n0 + wn + ni * 16 + l15;
        float val = acc[mi][ni][j];
        if (EPI == 0) {
          const int bb = r >> 12, t2 = r & (T_ - 1);
          const int hh = c >> 7, dh = c & (DH_ - 1);
          ((bf16*)dst)[(((size_t)(bb * H_ + hh)) * T_ + t2) * DH_ + dh] = __float2bfloat16(val);
        } else if (EPI == 2) {
          resid[(size_t)r * N + c] += val + bias[c];
        } else if (EPI == 3) {
          const float xg = val + bias[c];
          ((bf16*)dst)[(size_t)r * N + c] =
              __float2bfloat16(0.5f * xg * (1.0f + erff(xg * 0.70710678118654752440f)));
        } else if (EPI == 4) {
          ((bf16*)dst)[(size_t)r * N + c] = __float2bfloat16(val);
        } else if (EPI == 6) {
          const int bb = r >> 12, t2 = r & (T_ - 1);
          if (c < 1024) {
            const int hh = c >> 7, dh = c & (DH_ - 1);
            ((bf16*)dst)[(((size_t)(bb * H_ + hh)) * T_ + t2) * DH_ + dh] = __float2bfloat16(val);
          } else {
            const int c2 = c - 1024;
            const int hh = c2 >> 7, dh = c2 & (DH_ - 1);
            ((bf16*)resid)[(((size_t)(bb * H_ + hh)) * T_ + t2) * DH_ + dh] = __float2bfloat16(val);
          }
        }
      }
    }
  }
}

// ---------------- bucket argmax (fallback path) ----------------
__global__ void bucket_kernel(const bf16* __restrict__ rotv, uint8_t* __restrict__ buckets) {
  const int idx = blockIdx.x * 256 + threadIdx.x;
  if (idx >= BH_ * T_ * NH_) return;
  const int row = idx >> 3, hh = idx & 7;
  const bf16* p = rotv + (size_t)row * 256 + hh * 32;
  float vmax = -3e38f, vmin = 3e38f;
  int imax = 0, imin = 0;
  for (int r = 0; r < 32; ++r) {
    const float xv = __bfloat162float(p[r]);
    if (xv > vmax) { vmax = xv; imax = r; }
    if (xv < vmin) { vmin = xv; imin = r; }
  }
  const int bkt = (vmax >= -vmin) ? imax : 32 + imin;
  const int bh = row >> 12, t = row & (T_ - 1);
  buckets[((size_t)(bh * 8 + hh) << 12) + t] = (uint8_t)bkt;
}

// ---------------- stable counting sort per (bh, hash); also inverse perm ----------------
__global__ __launch_bounds__(256)
void sort_kernel(const uint8_t* __restrict__ buckets, int* __restrict__ st,
                 int* __restrict__ inv) {
  __shared__ uint8_t bk[T_];
  __shared__ int wsum[4];
  const int tid = threadIdx.x;
  const int grp = blockIdx.x;  // bh*8 + h
  const uint8_t* src = buckets + (size_t)grp * T_;
  int* dst = st + (size_t)grp * T_;
  int* ivd = inv ? inv + (size_t)grp * T_ : nullptr;
  for (int i = tid; i < T_; i += 256) bk[i] = src[i];
  __syncthreads();
  const int lane = tid & 63, w = tid >> 6;
  const int t0 = tid * 16;
  int base = 0;
  for (int b = 0; b < 64; ++b) {
    int cnt = 0;
#pragma unroll
    for (int j = 0; j < 16; ++j) cnt += (bk[t0 + j] == b) ? 1 : 0;
    int incl = cnt;
    for (int o = 1; o < 64; o <<= 1) {
      int vv = __shfl_up(incl, o, 64);
      if (lane >= o) incl += vv;
    }
    if (lane == 63) wsum[w] = incl;
    __syncthreads();
    int wo = 0;
    for (int i = 0; i < w; ++i) wo += wsum[i];
    const int tot = wsum[0] + wsum[1] + wsum[2] + wsum[3];
    int pos = base + wo + incl - cnt;
    for (int j = 0; j < 16; ++j)
      if (bk[t0 + j] == b) {
        dst[pos] = t0 + j;
        if (ivd) ivd[t0 + j] = pos;
        ++pos;
      }
    base += tot;
    __syncthreads();
  }
}

// ---------------- qk row L2-normalize: qkn = qk/|qk|, qnorm = |qk| ----------------
__global__ __launch_bounds__(256)
void qknorm_kernel(const bf16* __restrict__ qk, bf16* __restrict__ qkn,
                   float* __restrict__ qnorm) {
  const int wid = (blockIdx.x * 256 + threadIdx.x) >> 6;
  const int lane = threadIdx.x & 63;
  if (wid >= BH_ * T_) return;
  const bf16* src = qk + (size_t)wid * DH_;
  const float a = __bfloat162float(src[2 * lane]);
  const float b = __bfloat162float(src[2 * lane + 1]);
  float ss = a * a + b * b;
#pragma unroll
  for (int o = 1; o < 64; o <<= 1) ss += __shfl_xor(ss, o, 64);
  const float nrm = sqrtf(ss);
  const float sc = 1.0f / fmaxf(nrm, 1e-12f);
  bf16* d = qkn + (size_t)wid * DH_;
  d[2 * lane] = __float2bfloat16(a * sc);
  d[2 * lane + 1] = __float2bfloat16(b * sc);
  if (lane == 0) qnorm[wid] = nrm;
}

// ================== BIG PATH: per-hash sorted-output attention ==================
// XCD-clustered 1-D grid (R11). LDS overlay + T14 split V staging (R13).
// R15: stkv row-index reads hoisted out of the softmax j-loop (VALU-bound kernel).
__global__ __launch_bounds__(256)
void attn_sorted(const bf16* __restrict__ qkn, const float* __restrict__ qnormg,
                 const bf16* __restrict__ v, const int* __restrict__ st,
                 bf16* __restrict__ so, float* __restrict__ lseg) {
  __shared__ __align__(16) bf16 sK[128 * 136];       // rows 0..63 -> sP; rows 64..127 -> sVT-hi
  __shared__ __align__(16) uint32_t sVTlo[64 * 68];  // sVT rows (d) 0..63
  __shared__ int stkv[128];
  __shared__ float snq[64];

  const int tid = threadIdx.x;
  const int lin = blockIdx.x;
  const int xcd = lin & 7;
  const int wq = lin >> 3;
  const int bh = xcd + ((wq >> 9) << 3);
  const int rem = wq & 511;
  const int hh = rem >> 6;
  const int cb = rem & 63;

  const int cg = hh * NB_ + cb;
  const int pg = (cg + NC_ - 1) & (NC_ - 1);
  const int* stb = st + (size_t)bh * (NH_ * T_);
  if (tid < 128) {
    const int p = (tid < 64) ? (cg * BS_ + tid) : (pg * BS_ + tid - 64);
    stkv[tid] = stb[p];
  }
  __syncthreads();

  const size_t vbase = (size_t)bh * T_ * DH_;
  if (tid < 64) snq[tid] = qnormg[(size_t)bh * T_ + stkv[tid]];
  {
    const int part = tid & 15, row = tid >> 4;
    for (int r0 = 0; r0 < 128; r0 += 16) {
      const int rr = r0 + row;
      const int t = stkv[rr];
      *(float4*)&sK[rr * 136 + part * 8] = *(const float4*)(qkn + vbase + (size_t)t * DH_ + part * 8);
    }
  }
  float4 va[4], vb[4];
#pragma unroll
  for (int it = 0; it < 4; ++it) {
    const int idx = it * 256 + tid;
    const int g = idx & 15, kp = idx >> 4;
    va[it] = *(const float4*)(v + vbase + (size_t)stkv[2 * kp] * DH_ + g * 8);
    vb[it] = *(const float4*)(v + vbase + (size_t)stkv[2 * kp + 1] * DH_ + g * 8);
  }
  __syncthreads();

  const int lane = tid & 63;
  const int w = tid >> 6;
  const int l15 = lane & 15, lq = lane >> 4;

  f32x4 acc[8];
#pragma unroll
  for (int i = 0; i < 8; ++i) acc[i] = (f32x4){0.f, 0.f, 0.f, 0.f};
#pragma unroll
  for (int kk = 0; kk < 4; ++kk) {
    short8 af = *(const short8*)&sK[(w * 16 + l15) * 136 + lq * 8 + kk * 32];
#pragma unroll
    for (int ni = 0; ni < 8; ++ni) {
      short8 bf = *(const short8*)&sK[(ni * 16 + l15) * 136 + lq * 8 + kk * 32];
      acc[ni] = __builtin_amdgcn_mfma_f32_16x16x32_bf16(af, bf, acc[ni], 0, 0, 0);
    }
  }
  __syncthreads();

  bf16* sP = sK;
  uint32_t* sVThi = (uint32_t*)(sK + 64 * 136);

  // hoisted: key positions per column group (j-invariant)
  int tkv[8];
#pragma unroll
  for (int ni = 0; ni < 8; ++ni) tkv[ni] = stkv[ni * 16 + l15];

  float lsev[4];
  const float scale = 0.08838834764831845f;
#pragma unroll
  for (int j = 0; j < 4; ++j) {
    const int row = w * 16 + lq * 4 + j;
    const int tq = stkv[row];
    const float rowsc = scale * snq[row];
    float mx = -3.0e38f;
#pragma unroll
    for (int ni = 0; ni < 8; ++ni) {
      float val = acc[ni][j] * rowsc;
      if (tq < tkv[ni]) val = -1e9f;
      else if (tq == tkv[ni]) val = -5e4f;
      acc[ni][j] = val;
      mx = fmaxf(mx, val);
    }
#pragma unroll
    for (int o = 1; o < 16; o <<= 1) mx = fmaxf(mx, __shfl_xor(mx, o, 64));
    float ex[8];
    float se = 0.f;
#pragma unroll
    for (int ni = 0; ni < 8; ++ni) { ex[ni] = __expf(acc[ni][j] - mx); se += ex[ni]; }
#pragma unroll
    for (int o = 1; o < 16; o <<= 1) se += __shfl_xor(se, o, 64);
    const float inv = 1.0f / se;
#pragma unroll
    for (int ni = 0; ni < 8; ++ni)
      sP[row * 136 + ni * 16 + l15] = __float2bfloat16(ex[ni] * inv);
    lsev[j] = mx + __logf(se);
  }

#pragma unroll
  for (int it = 0; it < 4; ++it) {
    const int idx = it * 256 + tid;
    const int g = idx & 15, kp = idx >> 4;
    const unsigned short* ua = (const unsigned short*)&va[it];
    const unsigned short* ub = (const unsigned short*)&vb[it];
    const int csw = (g & 7) << 2;
    uint32_t* vdst = (g < 8) ? (sVTlo + g * 8 * 68) : (sVThi + (g - 8) * 8 * 68);
#pragma unroll
    for (int j = 0; j < 8; ++j)
      vdst[j * 68 + (kp ^ csw)] = (uint32_t)ua[j] | ((uint32_t)ub[j] << 16);
  }
  __syncthreads();

  f32x4 acc2[8];
#pragma unroll
  for (int i = 0; i < 8; ++i) acc2[i] = (f32x4){0.f, 0.f, 0.f, 0.f};
#pragma unroll
  for (int kk = 0; kk < 4; ++kk) {
    short8 pa = *(const short8*)&sP[(w * 16 + l15) * 136 + lq * 8 + kk * 32];
#pragma unroll
    for (int ni = 0; ni < 8; ++ni) {
      const int row = ni * 16 + l15;
      const int col = (lq * 4 + kk * 16) ^ (((row >> 3) & 7) << 2);
      const uint32_t* vrow = (ni < 4) ? (sVTlo + row * 68) : (sVThi + (row - 64) * 68);
      short8 bv = *(const short8*)&vrow[col];
      acc2[ni] = __builtin_amdgcn_mfma_f32_16x16x32_bf16(pa, bv, acc2[ni], 0, 0, 0);
    }
  }

  const size_t sobase = ((size_t)(hh * BH_ + bh) * T_ + (size_t)cb * BS_) * DH_;
#pragma unroll
  for (int j = 0; j < 4; ++j) {
    const int row = w * 16 + lq * 4 + j;
    if (l15 == 0)
      lseg[(size_t)(hh * BH_ + bh) * T_ + cb * BS_ + row] = lsev[j];
    bf16* orow = so + sobase + (size_t)row * DH_;
#pragma unroll
    for (int ni = 0; ni < 8; ++ni) {
      bf16 hv = __float2bfloat16(acc2[ni][j]);
      __builtin_nontemporal_store(*(unsigned short*)&hv,
                                  (unsigned short*)(orow + ni * 16 + l15));
    }
  }
}

// combine across hashes: one wave per token; gather 8 so-rows via inverse perm.
__global__ __launch_bounds__(256)
void combine2_kernel(const bf16* __restrict__ so, const float* __restrict__ lseg,
                     const int* __restrict__ ipos, bf16* __restrict__ ocomb) {
  const int gw = (blockIdx.x * 256 + threadIdx.x) >> 6;
  const int lane = threadIdx.x & 63;
  if (gw >= BH_ * T_) return;
  const int bh = gw >> 12, t = gw & (T_ - 1);
  float lse8 = -3.0e38f;
  int p8 = 0;
  if (lane < 8) {
    p8 = ipos[((size_t)bh * NH_ + lane) * T_ + t];
    lse8 = lseg[((size_t)lane * BH_ + bh) * T_ + p8];
  }
  float m = -3.0e38f;
#pragma unroll
  for (int h = 0; h < 8; ++h) m = fmaxf(m, __shfl(lse8, h, 64));
  float s = 0.f;
#pragma unroll
  for (int h = 0; h < 8; ++h) s += __expf(__shfl(lse8, h, 64) - m);
  const float invs = 1.0f / s;
  float a0 = 0.f, a1 = 0.f;
#pragma unroll
  for (int h = 0; h < 8; ++h) {
    const int ph = __shfl(p8, h, 64);
    const float wh = __expf(__shfl(lse8, h, 64) - m) * invs;
    const unsigned short* rp =
        (const unsigned short*)(so + (((size_t)h * BH_ + bh) * T_ + ph) * DH_ + lane * 2);
    unsigned short u0 = __builtin_nontemporal_load(rp);
    unsigned short u1 = __builtin_nontemporal_load(rp + 1);
    a0 += wh * __bfloat162float(*(const bf16*)&u0);
    a1 += wh * __bfloat162float(*(const bf16*)&u1);
  }
  const int bb = bh >> 3, hd = bh & 7;
  bf16* dp = ocomb + ((size_t)(bb * T_ + t)) * D_ + hd * DH_ + lane * 2;
  dp[0] = __float2bfloat16(a0);
  dp[1] = __float2bfloat16(a1);
}

// ================== FALLBACK PATH kernels (unchanged) ==================
__global__ __launch_bounds__(256)
void attn_kernel(const bf16* __restrict__ qkn, const float* __restrict__ qnormg,
                 const bf16* __restrict__ v, const int* __restrict__ st,
                 float* __restrict__ mg, float* __restrict__ sg,
                 float* __restrict__ oac, int hh) {
  __shared__ __align__(16) bf16 sK[128 * 136];
  __shared__ __align__(16) uint32_t sVT[128][68];
  __shared__ int stkv[128];
  __shared__ float snq[64];

  const int tid = threadIdx.x;
  const int cb = blockIdx.x;
  const int bh = blockIdx.y;
  const int cg = hh * NB_ + cb;
  const int pg = (cg + NC_ - 1) & (NC_ - 1);
  const int* stb = st + (size_t)bh * (NH_ * T_);
  if (tid < 128) {
    const int p = (tid < 64) ? (cg * BS_ + tid) : (pg * BS_ + tid - 64);
    stkv[tid] = stb[p];
  }
  __syncthreads();

  const size_t vbase = (size_t)bh * T_ * DH_;
  if (tid < 64) snq[tid] = qnormg[(size_t)bh * T_ + stkv[tid]];
  {
    const int part = tid & 15, row = tid >> 4;
    for (int r0 = 0; r0 < 128; r0 += 16) {
      const int rr = r0 + row;
      const int t = stkv[rr];
      *(float4*)&sK[rr * 136 + part * 8] = *(const float4*)(qkn + vbase + (size_t)t * DH_ + part * 8);
    }
  }
  {
    for (int it = 0; it < 4; ++it) {
      const int idx = it * 256 + tid;
      const int g = idx & 15, kp = idx >> 4;
      const int t0 = stkv[2 * kp], t1 = stkv[2 * kp + 1];
      float4 a = *(const float4*)(v + vbase + (size_t)t0 * DH_ + g * 8);
      float4 b = *(const float4*)(v + vbase + (size_t)t1 * DH_ + g * 8);
      const unsigned short* ua = (const unsigned short*)&a;
      const unsigned short* ub = (const unsigned short*)&b;
#pragma unroll
      for (int j = 0; j < 8; ++j)
        sVT[g * 8 + j][kp] = (uint32_t)ua[j] | ((uint32_t)ub[j] << 16);
    }
  }
  __syncthreads();

  const int lane = tid & 63;
  const int w = tid >> 6;
  const int l15 = lane & 15, lq = lane >> 4;

  f32x4 acc[8];
#pragma unroll
  for (int i = 0; i < 8; ++i) acc[i] = (f32x4){0.f, 0.f, 0.f, 0.f};
#pragma unroll
  for (int kk = 0; kk < 4; ++kk) {
    short8 af = *(const short8*)&sK[(w * 16 + l15) * 136 + lq * 8 + kk * 32];
#pragma unroll
    for (int ni = 0; ni < 8; ++ni) {
      short8 bf = *(const short8*)&sK[(ni * 16 + l15) * 136 + lq * 8 + kk * 32];
      acc[ni] = __builtin_amdgcn_mfma_f32_16x16x32_bf16(af, bf, acc[ni], 0, 0, 0);
    }
  }
  __syncthreads();

  bf16* sP = sK;

  float lsev[4];
  const float scale = 0.08838834764831845f;
#pragma unroll
  for (int j = 0; j < 4; ++j) {
    const int row = w * 16 + lq * 4 + j;
    const int tq = stkv[row];
    const float rowsc = scale * snq[row];
    float mx = -3.0e38f;
#pragma unroll
    for (int ni = 0; ni < 8; ++ni) {
      const int tk = stkv[ni * 16 + l15];
      float val = acc[ni][j] * rowsc;
      if (tq < tk) val = -1e9f;
      else if (tq == tk) val = -5e4f;
      acc[ni][j] = val;
      mx = fmaxf(mx, val);
    }
#pragma unroll
    for (int o = 1; o < 16; o <<= 1) mx = fmaxf(mx, __shfl_xor(mx, o, 64));
    float se = 0.f;
#pragma unroll
    for (int ni = 0; ni < 8; ++ni) se += __expf(acc[ni][j] - mx);
#pragma unroll
    for (int o = 1; o < 16; o <<= 1) se += __shfl_xor(se, o, 64);
    const float inv = 1.0f / se;
#pragma unroll
    for (int ni = 0; ni < 8; ++ni)
      sP[row * 136 + ni * 16 + l15] = __float2bfloat16(__expf(acc[ni][j] - mx) * inv);
    lsev[j] = mx + __logf(se);
  }
  __syncthreads();

  f32x4 acc2[8];
#pragma unroll
  for (int i = 0; i < 8; ++i) acc2[i] = (f32x4){0.f, 0.f, 0.f, 0.f};
#pragma unroll
  for (int kk = 0; kk < 4; ++kk) {
    short8 pa = *(const short8*)&sP[(w * 16 + l15) * 136 + lq * 8 + kk * 32];
#pragma unroll
    for (int ni = 0; ni < 8; ++ni) {
      short8 bv = *(const short8*)&sVT[ni * 16 + l15][lq * 4 + kk * 16];
      acc2[ni] = __builtin_amdgcn_mfma_f32_16x16x32_bf16(pa, bv, acc2[ni], 0, 0, 0);
    }
  }

#pragma unroll
  for (int j = 0; j < 4; ++j) {
    const int row = w * 16 + lq * 4 + j;
    const int t = stkv[row];
    const size_t gi = (size_t)bh * T_ + t;
    const float ls = lsev[j];
    float* orow = oac + gi * DH_;
    if (hh == 0) {
      if (l15 == 0) { sg[gi] = 1.0f; mg[gi] = ls; }
#pragma unroll
      for (int ni = 0; ni < 8; ++ni) orow[ni * 16 + l15] = acc2[ni][j];
    } else {
      const float mo = mg[gi];
      const float mn = fmaxf(mo, ls);
      const float al = __expf(mo - mn);
      const float be = __expf(ls - mn);
      if (l15 == 0) { sg[gi] = sg[gi] * al + be; mg[gi] = mn; }
#pragma unroll
      for (int ni = 0; ni < 8; ++ni) {
        const int c = ni * 16 + l15;
        orow[c] = orow[c] * al + be * acc2[ni][j];
      }
    }
  }
}

__global__ void combine_kernel(const float* __restrict__ oac, const float* __restrict__ sg,
                               bf16* __restrict__ ocomb) {
  const int idx = blockIdx.x * 256 + threadIdx.x;
  if (idx >= BH_ * T_ * DH_ / 4) return;
  const int rowtok = idx >> 5;
  const int gsub = idx & 31;
  const float inv = 1.0f / sg[rowtok];
  float4 ov = ((const float4*)oac)[idx];
  const int bh = rowtok >> 12, t = rowtok & (T_ - 1);
  const int bb = bh >> 3, hd = bh & 7;
  bf16* dp = ocomb + ((size_t)(bb * T_ + t)) * D_ + hd * DH_ + gsub * 4;
  dp[0] = __float2bfloat16(ov.x * inv);
  dp[1] = __float2bfloat16(ov.y * inv);
  dp[2] = __float2bfloat16(ov.z * inv);
  dp[3] = __float2bfloat16(ov.w * inv);
}

// ---------------- final mean pool ----------------
__global__ void pool_partial(const float* __restrict__ x1, const float* __restrict__ x2,
                             float* __restrict__ part) {
  const int b = blockIdx.y, slice = blockIdx.x;
  const int tid = threadIdx.x;
  float acc[4] = {0.f, 0.f, 0.f, 0.f};
  for (int r = 0; r < 32; ++r) {
    const size_t base = ((size_t)b * T_ + slice * 32 + r) * D_;
#pragma unroll
    for (int i = 0; i < 4; ++i) {
      const int c = tid + i * 256;
      acc[i] += x1[base + c] + x2[base + c];
    }
  }
#pragma unroll
  for (int i = 0; i < 4; ++i)
    part[((size_t)(b * 128 + slice)) * D_ + tid + i * 256] = acc[i];
}

__global__ void pool_reduce(const float* __restrict__ part, float* __restrict__ out) {
  const int idx = blockIdx.x * 256 + threadIdx.x;
  if (idx >= B_ * D_) return;
  const int b = idx >> 10, d = idx & 1023;
  float s = 0.f;
  for (int k = 0; k < 128; ++k) s += part[((size_t)(b * 128 + k)) * D_ + d];
  out[idx] = s * (0.5f / T_);
}

extern "C" void kernel_launch(void* const* d_in, const int* in_sizes, int n_in,
                              void* d_out, int out_size, void* d_ws, size_t ws_size,
                              hipStream_t stream) {
  (void)in_sizes; (void)n_in; (void)out_size;
  const float* x    = (const float*)d_in[0];
  const float* Wqk  = (const float*)d_in[1];
  const float* Wv   = (const float*)d_in[2];
  const float* Wout = (const float*)d_in[3];
  const float* bout = (const float*)d_in[4];
  const float* ln1g = (const float*)d_in[5];
  const float* ln1b = (const float*)d_in[6];
  const float* W1   = (const float*)d_in[7];
  const float* b1   = (const float*)d_in[8];
  const float* W2   = (const float*)d_in[9];
  const float* b2   = (const float*)d_in[10];
  const float* ln2g = (const float*)d_in[11];
  const float* ln2b = (const float*)d_in[12];
  const float* rot  = (const float*)d_in[13];
  float* out = (float*)d_out;

  char* ws = (char*)d_ws;
  const dim3 blk(256);
  const dim3 blk512(512);

  // ---------- BIG plan (~245.3 MiB): per-hash sorted outputs ----------
  {
    size_t off = 0;
    auto alloc = [&](size_t b) { size_t o = off; off += (b + 255) & ~(size_t)255; return o; };
    const size_t o_x1  = alloc((size_t)B_ * T_ * D_ * 4);
    const size_t o_x2  = alloc((size_t)B_ * T_ * D_ * 4);
    const size_t o_hq  = alloc((size_t)B_ * T_ * D_ * 2);       // h / qkn
    const size_t o_qk  = alloc((size_t)BH_ * T_ * DH_ * 2);     // qk / ocomb
    const size_t o_vv  = alloc((size_t)BH_ * T_ * DH_ * 2);     // v
    const size_t o_so  = alloc((size_t)NH_ * BH_ * T_ * DH_ * 2);  // 128 MiB, heavy aliasing
    const size_t o_lse = alloc((size_t)NH_ * BH_ * T_ * 4);
    const size_t o_st  = alloc((size_t)BH_ * NH_ * T_ * 4);
    const size_t o_ip  = alloc((size_t)BH_ * NH_ * T_ * 4);
    const size_t o_bkt = alloc((size_t)BH_ * NH_ * T_);
    const size_t o_qn  = alloc((size_t)BH_ * T_ * 4);
    const size_t o_part = alloc((size_t)B_ * 128 * D_ * 4);

    if (off <= ws_size) {
      float* x1   = (float*)(ws + o_x1);
      float* x2   = (float*)(ws + o_x2);
      bf16*  h    = (bf16*)(ws + o_hq);
      bf16*  qkn  = (bf16*)(ws + o_hq);
      bf16*  qk   = (bf16*)(ws + o_qk);
      bf16*  ocomb = (bf16*)(ws + o_qk);
      bf16*  vv   = (bf16*)(ws + o_vv);
      bf16*  so   = (bf16*)(ws + o_so);
      float* lse  = (float*)(ws + o_lse);
      int*   st   = (int*)(ws + o_st);
      int*   ip   = (int*)(ws + o_ip);
      uint8_t* bkt = (uint8_t*)(ws + o_bkt);
      float* qn   = (float*)(ws + o_qn);
      float* part = (float*)(ws + o_part);
      bf16* wqkT = (bf16*)(ws + o_so);                      // pre-attn; wvT contiguous after
      bf16* wvT  = wqkT + (size_t)D_ * D_;
      bf16* rotT = wvT + (size_t)D_ * D_;
      bf16* woT  = (bf16*)(ws + o_so);                      // post-combine2
      bf16* ffh  = (bf16*)(ws + o_so);                      // FF (64 MiB)
      bf16* w1T  = (bf16*)(ws + o_so + ((size_t)64 << 20));
      bf16* w2T  = w1T + (size_t)D_ * FF_;

      copy2_kernel<<<dim3(B_ * T_ * D_ / 4 / 256), blk, 0, stream>>>(x, x1, x2);

      for (int l = 0; l < L_; ++l) {
        transpose_cvt<<<dim3(32, 32), blk, 0, stream>>>(Wqk + (size_t)l * D_ * D_, wqkT, D_, D_);
        transpose_cvt<<<dim3(32, 32), blk, 0, stream>>>(Wv + (size_t)l * D_ * D_, wvT, D_, D_);
        transpose_cvt<<<dim3(8, 4), blk, 0, stream>>>(rot + (size_t)l * DH_ * 256, rotT, DH_, 256);

        ln_kernel<<<dim3(B_ * T_), blk, 0, stream>>>(x2, ln1g + l * D_, ln1b + l * D_, h);
        // fused QK+V projection on the proven 2-phase kernel (B = [wqkT ; wvT])
        gemm_bt_k<6><<<dim3(16, 64), blk512, 0, stream>>>(h, wqkT, qk, nullptr, (float*)vv,
                                                          B_ * T_, 2048, D_);
        qknorm_kernel<<<dim3(BH_ * T_ / 4), blk, 0, stream>>>(qk, qkn, qn);
        gemm_bt_k<5><<<dim3(2, 512), blk512, 0, stream>>>(qkn, rotT, bkt, nullptr, nullptr, BH_ * T_, 256, DH_);
        sort_kernel<<<dim3(BH_ * NH_), blk, 0, stream>>>(bkt, st, ip);
        attn_sorted<<<dim3(NB_ * BH_ * NH_), blk, 0, stream>>>(qkn, qn, vv, st, so, lse);
        combine2_kernel<<<dim3(BH_ * T_ / 4), blk, 0, stream>>>(so, lse, ip, ocomb);
        transpose_cvt<<<dim3(32, 32), blk, 0, stream>>>(Wout + (size_t)l * D_ * D_, woT, D_, D_);
        gemm_bt_k<2><<<dim3(8, 64), blk512, 0, stream>>>(ocomb, woT, nullptr, bout + l * D_, x1, B_ * T_, D_, D_);

        transpose_cvt<<<dim3(128, 32), blk, 0, stream>>>(W1 + (size_t)l * D_ * FF_, w1T, D_, FF_);
        transpose_cvt<<<dim3(32, 128), blk, 0, stream>>>(W2 + (size_t)l * FF_ * D_, w2T, FF_, D_);
        ln_kernel<<<dim3(B_ * T_), blk, 0, stream>>>(x1, ln2g + l * D_, ln2b + l * D_, h);
        gemm_bt_k<3><<<dim3(32, 64), blk512, 0, stream>>>(h, w1T, ffh, b1 + l * FF_, nullptr, B_ * T_, FF_, D_);
        gemm_bt_k<2><<<dim3(8, 64), blk512, 0, stream>>>(ffh, w2T, nullptr, b2 + l * D_, x2, B_ * T_, D_, FF_);
      }

      pool_partial<<<dim3(128, B_), blk, 0, stream>>>(x1, x2, part);
      pool_reduce<<<dim3((B_ * D_ + 255) / 256), blk, 0, stream>>>(part, out);
      return;
    }
  }

  // ---------- FALLBACK plan (~164.3 MiB) ----------
  size_t off = 0;
  auto alloc = [&](size_t b) { size_t o = off; off += (b + 255) & ~(size_t)255; return o; };
  const size_t o_x1   = alloc((size_t)B_ * T_ * D_ * 4);
  const size_t o_x2   = alloc((size_t)B_ * T_ * D_ * 4);
  const size_t o_hq   = alloc((size_t)B_ * T_ * D_ * 2);
  const size_t o_qk   = alloc((size_t)BH_ * T_ * DH_ * 2);
  const size_t o_vv   = alloc((size_t)BH_ * T_ * DH_ * 2);
  const size_t o_oac  = alloc((size_t)BH_ * T_ * DH_ * 4);
  const size_t o_st   = alloc((size_t)BH_ * NH_ * T_ * 4);
  const size_t o_bkt  = alloc((size_t)BH_ * NH_ * T_);
  const size_t o_mg   = alloc((size_t)BH_ * T_ * 4);
  const size_t o_sg   = alloc((size_t)BH_ * T_ * 4);
  const size_t o_qn   = alloc((size_t)BH_ * T_ * 4);
  const size_t o_part = alloc((size_t)B_ * 128 * D_ * 4);
  const size_t o_w    = alloc((size_t)D_ * FF_ * 2 * 2);
  if (off > ws_size) {
    diag_kernel<<<dim3(1), dim3(64), 0, stream>>>(out, (float)ws_size, (float)off);
    return;
  }

  float* x1   = (float*)(ws + o_x1);
  float* x2   = (float*)(ws + o_x2);
  bf16*  h    = (bf16*)(ws + o_hq);
  bf16*  qkn  = (bf16*)(ws + o_hq);
  bf16*  qk   = (bf16*)(ws + o_qk);
  bf16*  ocomb = (bf16*)(ws + o_qk);
  bf16*  vv   = (bf16*)(ws + o_vv);
  float* oac  = (float*)(ws + o_oac);
  bf16*  rotd = (bf16*)(ws + o_oac);
  bf16*  ffh  = (bf16*)(ws + o_qk);
  int*   st   = (int*)(ws + o_st);
  uint8_t* bkt = (uint8_t*)(ws + o_bkt);
  float* mg   = (float*)(ws + o_mg);
  float* sg   = (float*)(ws + o_sg);
  float* qn   = (float*)(ws + o_qn);
  float* part = (float*)(ws + o_part);
  bf16* wqkT = (bf16*)(ws + o_w);
  bf16* wvT  = (bf16*)(ws + o_w + (size_t)D_ * D_ * 2);
  bf16* woT  = (bf16*)(ws + o_w + (size_t)D_ * D_ * 2 * 2);
  bf16* rotT = (bf16*)(ws + o_w + (size_t)D_ * D_ * 2 * 3);
  bf16* w1T  = (bf16*)(ws + o_w);
  bf16* w2T  = (bf16*)(ws + o_w + (size_t)D_ * FF_ * 2);

  copy2_kernel<<<dim3(B_ * T_ * D_ / 4 / 256), blk, 0, stream>>>(x, x1, x2);

  for (int l = 0; l < L_; ++l) {
    transpose_cvt<<<dim3(32, 32), blk, 0, stream>>>(Wqk + (size_t)l * D_ * D_, wqkT, D_, D_);
    transpose_cvt<<<dim3(32, 32), blk, 0, stream>>>(Wv + (size_t)l * D_ * D_, wvT, D_, D_);
    transpose_cvt<<<dim3(32, 32), blk, 0, stream>>>(Wout + (size_t)l * D_ * D_, woT, D_, D_);
    transpose_cvt<<<dim3(8, 4), blk, 0, stream>>>(rot + (size_t)l * DH_ * 256, rotT, DH_, 256);

    ln_kernel<<<dim3(B_ * T_), blk, 0, stream>>>(x2, ln1g + l * D_, ln1b + l * D_, h);
    gemm_bt_k<0><<<dim3(8, 64), blk512, 0, stream>>>(h, wqkT, qk, nullptr, nullptr, B_ * T_, D_, D_);
    gemm_bt_k<0><<<dim3(8, 64), blk512, 0, stream>>>(h, wvT, vv, nullptr, nullptr, B_ * T_, D_, D_);
    qknorm_kernel<<<dim3(BH_ * T_ / 4), blk, 0, stream>>>(qk, qkn, qn);
    gemm_bt_k<4><<<dim3(2, 512), blk512, 0, stream>>>(qkn, rotT, rotd, nullptr, nullptr, BH_ * T_, 256, DH_);
    bucket_kernel<<<dim3(BH_ * T_ * NH_ / 256), blk, 0, stream>>>(rotd, bkt);
    sort_kernel<<<dim3(BH_ * NH_), blk, 0, stream>>>(bkt, st, nullptr);
    for (int hh = 0; hh < NH_; ++hh)
      attn_kernel<<<dim3(NB_, BH_), blk, 0, stream>>>(qkn, qn, vv, st, mg, sg, oac, hh);
    combine_kernel<<<dim3(BH_ * T_ * DH_ / 4 / 256), blk, 0, stream>>>(oac, sg, ocomb);
    gemm_bt_k<2><<<dim3(8, 64), blk512, 0, stream>>>(ocomb, woT, nullptr, bout + l * D_, x1, B_ * T_, D_, D_);

    transpose_cvt<<<dim3(128, 32), blk, 0, stream>>>(W1 + (size_t)l * D_ * FF_, w1T, D_, FF_);
    transpose_cvt<<<dim3(32, 128), blk, 0, stream>>>(W2 + (size_t)l * FF_ * D_, w2T, FF_, D_);

    ln_kernel<<<dim3(B_ * T_), blk, 0, stream>>>(x1, ln2g + l * D_, ln2b + l * D_, h);
    gemm_bt_k<3><<<dim3(32, 64), blk512, 0, stream>>>(h, w1T, ffh, b1 + l * FF_, nullptr, B_ * T_, FF_, D_);
    gemm_bt_k<2><<<dim3(8, 64), blk512, 0, stream>>>(ffh, w2T, nullptr, b2 + l * D_, x2, B_ * T_, D_, FF_);
  }

  pool_partial<<<dim3(128, B_), blk, 0, stream>>>(x1, x2, part);
  pool_reduce<<<dim3((B_ * D_ + 255) / 256), blk, 0, stream>>>(part, out);
}